// Round 2
// baseline (7097.327 us; speedup 1.0000x reference)
//
#include <hip/hip_runtime.h>
#include <hip/hip_bf16.h>

#define B_ 64
#define S_ 512
#define D_ 256
#define H_ 512

typedef __attribute__((ext_vector_type(8))) short bf16x8;
typedef __attribute__((ext_vector_type(4))) float f32x4;
typedef unsigned short ushort_t;

__device__ __forceinline__ ushort_t f2bf(float f) {
    __hip_bfloat16 h = __float2bfloat16(f);   // RNE rounding
    return *reinterpret_cast<ushort_t*>(&h);
}
__device__ __forceinline__ float sigmoid_f(float x) { return 1.f / (1.f + __expf(-x)); }
__device__ __forceinline__ float tanh_f(float x) { return 1.f - 2.f / (__expf(2.f * x) + 1.f); }

// grid: 64 blocks x 512 threads.
// block: group g = blockIdx&3 (batch rows g*16..g*16+15), slice s = blockIdx>>2 (h-cols s*32..s*32+31)
// wave w (0..7): gate = w>>1 (f,i,o,chat), half = w&1 -> 16 g-columns = one 16x16 MFMA n-tile.
// U/Wx B-fragments live in VGPRs for the whole kernel (loaded once, fp32->bf16 RNE).
// K = 256 (x.W) + 512 (h.U) per step, fused (no gx precompute buffer).
__global__ __launch_bounds__(512, 2) void lstm_rec(
    const float* __restrict__ X,
    const float* __restrict__ Wf, const float* __restrict__ Wi,
    const float* __restrict__ Wo, const float* __restrict__ Wc,
    const float* __restrict__ bfp, const float* __restrict__ bip,
    const float* __restrict__ bop, const float* __restrict__ bcp,
    const float* __restrict__ Uf, const float* __restrict__ Ui,
    const float* __restrict__ Uo, const float* __restrict__ Uc,
    const float* __restrict__ Wfc,
    float* __restrict__ pred, ushort_t* __restrict__ hbuf,
    unsigned int* __restrict__ cnt,
    float* __restrict__ outH, float* __restrict__ outC)
{
    // padded strides: 520/264 ushorts -> 1040/528 B row stride (16B-aligned, 2-way max bank alias)
    __shared__ ushort_t hS[16 * 520];
    __shared__ ushort_t xS[16 * 264];
    __shared__ float gact[4][16][36];
    __shared__ float cS[16][32];

    const int tid  = threadIdx.x;
    const int w    = tid >> 6;
    const int lane = tid & 63;
    const int q    = lane >> 4;      // quad for MFMA frag layout
    const int m    = lane & 15;      // A-row / C-col / B-col lane index
    const int gate = w >> 1;
    const int half = w & 1;
    const int g    = blockIdx.x & 3;
    const int s    = blockIdx.x >> 2;

    const int ncol = s * 32 + half * 16 + m;   // column in H-space for this lane

    const float* Ug = (gate == 0) ? Uf : (gate == 1) ? Ui : (gate == 2) ? Uo : Uc;
    const float* Wg = (gate == 0) ? Wf : (gate == 1) ? Wi : (gate == 2) ? Wo : Wc;
    const float* bg = (gate == 0) ? bfp : (gate == 1) ? bip : (gate == 2) ? bop : bcp;

    const float bias = bg[ncol];

    // ---- one-time: load B-fragments into registers (fp32 -> bf16 RNE) ----
    // B-frag layout (16x16x32): lane holds col n = lane&15, k = q*8 + j
    bf16x8 UF[16];
    #pragma unroll
    for (int ks = 0; ks < 16; ++ks) {
        bf16x8 v;
        #pragma unroll
        for (int j = 0; j < 8; ++j) {
            int k = ks * 32 + q * 8 + j;
            v[j] = (short)f2bf(Ug[k * H_ + ncol]);
        }
        UF[ks] = v;
    }
    bf16x8 WF[8];
    #pragma unroll
    for (int ks = 0; ks < 8; ++ks) {
        bf16x8 v;
        #pragma unroll
        for (int j = 0; j < 8; ++j) {
            int k = ks * 32 + q * 8 + j;
            v[j] = (short)f2bf(Wg[k * H_ + ncol]);
        }
        WF[ks] = v;
    }

    const int urow = tid >> 5;   // update-phase row (batch within group), 0..15
    const int ucol = tid & 31;   // update-phase col (h-col within slice), 0..31
    const float wfc_v = Wfc[s * 32 + ucol];

    cS[urow][ucol] = 0.f;   // c0 = 0 (ordered by first staging __syncthreads)

    for (int t = 0; t < S_; ++t) {
        // ---- stage x(t) [16x256] fp32->bf16 and h(t) [16x512] bf16 into LDS ----
        {
            // thread handles 8 consecutive x elements: row=tid>>5, col=(tid&31)*8
            const float* xsrc = &X[((size_t)(g * 16 + urow) * S_ + t) * D_ + ucol * 8];
            float4 a = *(const float4*)xsrc;
            float4 b = *(const float4*)(xsrc + 4);
            bf16x8 v;
            v[0] = (short)f2bf(a.x); v[1] = (short)f2bf(a.y);
            v[2] = (short)f2bf(a.z); v[3] = (short)f2bf(a.w);
            v[4] = (short)f2bf(b.x); v[5] = (short)f2bf(b.y);
            v[6] = (short)f2bf(b.z); v[7] = (short)f2bf(b.w);
            *(bf16x8*)&xS[urow * 264 + ucol * 8] = v;
        }
        #pragma unroll
        for (int it = 0; it < 2; ++it) {
            int c = tid + it * 512;
            int row = c >> 6, cv = (c & 63) * 8;
            *(bf16x8*)&hS[row * 520 + cv] =
                *(const bf16x8*)&hbuf[(size_t)((t % 3) * B_ + g * 16 + row) * H_ + cv];
        }
        __syncthreads();

        // ---- g = bias + x.W + h.U for this wave's 16 columns (two indep acc chains) ----
        f32x4 accA = {bias, bias, bias, bias};
        f32x4 accB = {0.f, 0.f, 0.f, 0.f};
        #pragma unroll
        for (int ks = 0; ks < 8; ++ks) {
            bf16x8 a = *(const bf16x8*)&xS[m * 264 + ks * 32 + q * 8];
            accA = __builtin_amdgcn_mfma_f32_16x16x32_bf16(a, WF[ks], accA, 0, 0, 0);
        }
        #pragma unroll
        for (int ks = 0; ks < 16; ++ks) {
            bf16x8 a = *(const bf16x8*)&hS[m * 520 + ks * 32 + q * 8];
            accB = __builtin_amdgcn_mfma_f32_16x16x32_bf16(a, UF[ks], accB, 0, 0, 0);
        }

        // activation; C-layout: col = lane&15, row = q*4 + j
        #pragma unroll
        for (int j = 0; j < 4; ++j) {
            float v = accA[j] + accB[j];
            v = (gate < 3) ? sigmoid_f(v) : tanh_f(v);
            gact[gate][q * 4 + j][half * 16 + m] = v;
        }
        __syncthreads();

        // ---- state update: one thread per (row,col) of [16,32] ----
        float fv  = gact[0][urow][ucol];
        float iv  = gact[1][urow][ucol];
        float ov  = gact[2][urow][ucol];
        float chv = gact[3][urow][ucol];
        float c_new = fv * cS[urow][ucol] + iv * chv;
        cS[urow][ucol] = c_new;
        float hv = ov * tanh_f(c_new);

        hbuf[(size_t)(((t + 1) % 3) * B_ + g * 16 + urow) * H_ + s * 32 + ucol] = f2bf(hv);

        // fused prediction head: pred[b,t] += sum_cols h*Wfc  (32-lane reduce + 1 atomic)
        float pv = hv * wfc_v;
        pv += __shfl_xor(pv, 16);
        pv += __shfl_xor(pv, 8);
        pv += __shfl_xor(pv, 4);
        pv += __shfl_xor(pv, 2);
        pv += __shfl_xor(pv, 1);
        if (ucol == 0) atomicAdd(&pred[(g * 16 + urow) * S_ + t], pv);

        if (t == S_ - 1) {
            outH[(g * 16 + urow) * H_ + s * 32 + ucol] = hv;      // fp32, pre-rounding
            outC[(g * 16 + urow) * H_ + s * 32 + ucol] = c_new;   // fp32
        }

        // ---- inter-WG barrier for this batch group (agent scope, cross-XCD safe) ----
        __syncthreads();   // all waves' hbuf stores issued before arrive
        if (tid == 0) {
            __hip_atomic_fetch_add(&cnt[g], 1u, __ATOMIC_RELEASE, __HIP_MEMORY_SCOPE_AGENT);
        }
        unsigned int target = 16u * (unsigned int)(t + 1);
        while (__hip_atomic_load(&cnt[g], __ATOMIC_ACQUIRE, __HIP_MEMORY_SCOPE_AGENT) < target) {
            __builtin_amdgcn_s_sleep(2);
        }
        // acquire executed by every thread -> caches invalidated before next staging reads
    }
}

__global__ void pred_fin(const float* __restrict__ pred,
                         const float* __restrict__ bfc,
                         float* __restrict__ out)
{
    int i = blockIdx.x * blockDim.x + threadIdx.x;
    if (i < B_ * S_) out[i] = pred[i] + bfc[0];
}

extern "C" void kernel_launch(void* const* d_in, const int* in_sizes, int n_in,
                              void* d_out, int out_size, void* d_ws, size_t ws_size,
                              hipStream_t stream) {
    const float* X   = (const float*)d_in[0];
    const float* Wf  = (const float*)d_in[1];
    const float* Wi  = (const float*)d_in[2];
    const float* Wo  = (const float*)d_in[3];
    const float* Wc  = (const float*)d_in[4];
    const float* bfp = (const float*)d_in[5];
    const float* bip = (const float*)d_in[6];
    const float* bop = (const float*)d_in[7];
    const float* bcp = (const float*)d_in[8];
    const float* Uf  = (const float*)d_in[9];
    const float* Ui  = (const float*)d_in[10];
    const float* Uo  = (const float*)d_in[11];
    const float* Uc  = (const float*)d_in[12];
    const float* Wfc = (const float*)d_in[13];
    const float* bfc = (const float*)d_in[14];

    // ws layout: pred fp32 [64][512] @0 (128KB) | hbuf bf16 [3][64][512] @131072 (192KB) | counters @327680
    float*        pred = (float*)d_ws;
    ushort_t*     hbuf = (ushort_t*)((char*)d_ws + 131072);
    unsigned int* cnt  = (unsigned int*)((char*)d_ws + 131072 + 196608);

    hipMemsetAsync(d_ws, 0, 131072 + 196608 + 256, stream);   // zero pred, h(0), counters

    float* out = (float*)d_out;
    lstm_rec<<<64, 512, 0, stream>>>(X, Wf, Wi, Wo, Wc, bfp, bip, bop, bcp,
                                     Uf, Ui, Uo, Uc, Wfc,
                                     pred, hbuf, cnt,
                                     out + 32768, out + 65536);
    pred_fin<<<128, 256, 0, stream>>>(pred, bfc, out);
}

// Round 3
// 2999.180 us; speedup vs baseline: 2.3664x; 2.3664x over previous
//
#include <hip/hip_runtime.h>
#include <hip/hip_bf16.h>

#define B_ 64
#define S_ 512
#define D_ 256
#define H_ 512

typedef __attribute__((ext_vector_type(8))) short bf16x8;
typedef __attribute__((ext_vector_type(4))) float f32x4;
typedef unsigned short ushort_t;

__device__ __forceinline__ ushort_t f2bf(float f) {
    __hip_bfloat16 h = __float2bfloat16(f);   // RNE rounding
    return *reinterpret_cast<ushort_t*>(&h);
}
__device__ __forceinline__ float sigmoid_f(float x) { return 1.f / (1.f + __expf(-x)); }
__device__ __forceinline__ float tanh_f(float x) { return 1.f - 2.f / (__expf(2.f * x) + 1.f); }

// grid: 32 blocks x 512 threads.
// block: group g = blockIdx&3 (batch rows g*16..g*16+15), slice s = blockIdx>>2 (0..7, h-cols s*64..s*64+63)
// wave w (0..7): gate = w>>1 (f,i,o,chat), half = w&1 -> TWO 16-col n-tiles:
//   ncol0 = s*64 + half*32 + m, ncol1 = ncol0 + 16.
// U/Wx B-fragments live in VGPRs for the whole kernel (fp32->bf16 RNE once).
// K = 256 (x.W) + 512 (h.U) per step, fused. 8 blocks per batch-group sync via
// single-poller counter barrier (cooperative-groups pattern).
__global__ __launch_bounds__(512, 2) void lstm_rec(
    const float* __restrict__ X,
    const float* __restrict__ Wf, const float* __restrict__ Wi,
    const float* __restrict__ Wo, const float* __restrict__ Wc,
    const float* __restrict__ bfp, const float* __restrict__ bip,
    const float* __restrict__ bop, const float* __restrict__ bcp,
    const float* __restrict__ Uf, const float* __restrict__ Ui,
    const float* __restrict__ Uo, const float* __restrict__ Uc,
    const float* __restrict__ Wfc,
    float* __restrict__ pred, ushort_t* __restrict__ hbuf,
    unsigned int* __restrict__ cnt,
    float* __restrict__ outH, float* __restrict__ outC)
{
    __shared__ ushort_t hS[16 * 520];   // 520-short stride: 16B-aligned rows
    __shared__ ushort_t xS[16 * 264];
    __shared__ float gact[4][16][68];
    __shared__ float cS[16][64];

    const int tid  = threadIdx.x;
    const int w    = tid >> 6;
    const int lane = tid & 63;
    const int q    = lane >> 4;      // quad for MFMA frag layout
    const int m    = lane & 15;      // A-row / B-col lane index
    const int gate = w >> 1;
    const int half = w & 1;
    const int g    = blockIdx.x & 3;
    const int s    = blockIdx.x >> 2;

    const int ncol0 = s * 64 + half * 32 + m;
    const int ncol1 = ncol0 + 16;

    const float* Ug = (gate == 0) ? Uf : (gate == 1) ? Ui : (gate == 2) ? Uo : Uc;
    const float* Wg = (gate == 0) ? Wf : (gate == 1) ? Wi : (gate == 2) ? Wo : Wc;
    const float* bg = (gate == 0) ? bfp : (gate == 1) ? bip : (gate == 2) ? bop : bcp;

    const float bias0 = bg[ncol0];
    const float bias1 = bg[ncol1];

    // ---- one-time: load B-fragments into registers (fp32 -> bf16 RNE) ----
    // B-frag layout (16x16x32): lane holds col n, k = q*8 + j
    bf16x8 UF[2][16];
    bf16x8 WF[2][8];
    #pragma unroll
    for (int tt = 0; tt < 2; ++tt) {
        const int nc = tt ? ncol1 : ncol0;
        #pragma unroll
        for (int ks = 0; ks < 16; ++ks) {
            bf16x8 v;
            #pragma unroll
            for (int j = 0; j < 8; ++j) {
                int k = ks * 32 + q * 8 + j;
                v[j] = (short)f2bf(Ug[k * H_ + nc]);
            }
            UF[tt][ks] = v;
        }
        #pragma unroll
        for (int ks = 0; ks < 8; ++ks) {
            bf16x8 v;
            #pragma unroll
            for (int j = 0; j < 8; ++j) {
                int k = ks * 32 + q * 8 + j;
                v[j] = (short)f2bf(Wg[k * H_ + nc]);
            }
            WF[tt][ks] = v;
        }
    }

    const int urow = tid >> 5;   // update-phase row (batch within group), 0..15
    const int ucol = tid & 31;   // update-phase col base; thread owns ucol and ucol+32
    const float wfc0 = Wfc[s * 64 + ucol];
    const float wfc1 = Wfc[s * 64 + ucol + 32];

    cS[urow][ucol]      = 0.f;   // c0 = 0 (ordered by first __syncthreads)
    cS[urow][ucol + 32] = 0.f;

    // preload x(0) into registers
    float4 xr0, xr1;
    {
        const float* xsrc = &X[((size_t)(g * 16 + urow) * S_ + 0) * D_ + ucol * 8];
        xr0 = *(const float4*)xsrc;
        xr1 = *(const float4*)(xsrc + 4);
    }

    for (int t = 0; t < S_; ++t) {
        // ---- stage x(t) (from prefetch regs) and h(t) [16x512] into LDS ----
        {
            bf16x8 v;
            v[0] = (short)f2bf(xr0.x); v[1] = (short)f2bf(xr0.y);
            v[2] = (short)f2bf(xr0.z); v[3] = (short)f2bf(xr0.w);
            v[4] = (short)f2bf(xr1.x); v[5] = (short)f2bf(xr1.y);
            v[6] = (short)f2bf(xr1.z); v[7] = (short)f2bf(xr1.w);
            *(bf16x8*)&xS[urow * 264 + ucol * 8] = v;
        }
        #pragma unroll
        for (int it = 0; it < 2; ++it) {
            int c = tid + it * 512;
            int row = c >> 6, cv = (c & 63) * 8;
            *(bf16x8*)&hS[row * 520 + cv] =
                *(const bf16x8*)&hbuf[(size_t)((t % 3) * B_ + g * 16 + row) * H_ + cv];
        }
        __syncthreads();

        // ---- g = bias + x.W + h.U for this wave's 2 x 16 columns (4 indep acc chains) ----
        f32x4 accA0 = {bias0, bias0, bias0, bias0};
        f32x4 accA1 = {bias1, bias1, bias1, bias1};
        f32x4 accB0 = {0.f, 0.f, 0.f, 0.f};
        f32x4 accB1 = {0.f, 0.f, 0.f, 0.f};
        #pragma unroll
        for (int ks = 0; ks < 8; ++ks) {
            bf16x8 a = *(const bf16x8*)&xS[m * 264 + ks * 32 + q * 8];
            accA0 = __builtin_amdgcn_mfma_f32_16x16x32_bf16(a, WF[0][ks], accA0, 0, 0, 0);
            accA1 = __builtin_amdgcn_mfma_f32_16x16x32_bf16(a, WF[1][ks], accA1, 0, 0, 0);
        }
        #pragma unroll
        for (int ks = 0; ks < 16; ++ks) {
            bf16x8 a = *(const bf16x8*)&hS[m * 520 + ks * 32 + q * 8];
            accB0 = __builtin_amdgcn_mfma_f32_16x16x32_bf16(a, UF[0][ks], accB0, 0, 0, 0);
            accB1 = __builtin_amdgcn_mfma_f32_16x16x32_bf16(a, UF[1][ks], accB1, 0, 0, 0);
        }

        // activation; C-layout: col = lane&15, row = q*4 + j
        #pragma unroll
        for (int j = 0; j < 4; ++j) {
            float v0 = accA0[j] + accB0[j];
            float v1 = accA1[j] + accB1[j];
            v0 = (gate < 3) ? sigmoid_f(v0) : tanh_f(v0);
            v1 = (gate < 3) ? sigmoid_f(v1) : tanh_f(v1);
            gact[gate][q * 4 + j][half * 32 + m]      = v0;
            gact[gate][q * 4 + j][half * 32 + 16 + m] = v1;
        }
        __syncthreads();

        // ---- state update: thread handles (urow, ucol) and (urow, ucol+32) ----
        float pv = 0.f;
        #pragma unroll
        for (int j = 0; j < 2; ++j) {
            int col = ucol + 32 * j;
            float fv  = gact[0][urow][col];
            float iv  = gact[1][urow][col];
            float ov  = gact[2][urow][col];
            float chv = gact[3][urow][col];
            float c_new = fv * cS[urow][col] + iv * chv;
            cS[urow][col] = c_new;
            float hv = ov * tanh_f(c_new);

            hbuf[(size_t)(((t + 1) % 3) * B_ + g * 16 + urow) * H_ + s * 64 + col] = f2bf(hv);
            pv += hv * (j ? wfc1 : wfc0);

            if (t == S_ - 1) {
                outH[(g * 16 + urow) * H_ + s * 64 + col] = hv;      // fp32, pre-rounding
                outC[(g * 16 + urow) * H_ + s * 64 + col] = c_new;   // fp32
            }
        }

        // fused prediction head: reduce 32 lanes (one row per half-wave) + 1 atomic
        pv += __shfl_xor(pv, 16);
        pv += __shfl_xor(pv, 8);
        pv += __shfl_xor(pv, 4);
        pv += __shfl_xor(pv, 2);
        pv += __shfl_xor(pv, 1);
        if (ucol == 0) atomicAdd(&pred[(g * 16 + urow) * S_ + t], pv);

        if (t < S_ - 1) {
            // ---- inter-block barrier for this batch group (single poller) ----
            __syncthreads();   // drains vmcnt: all hbuf stores complete before release

            // prefetch x(t+1) into registers while we wait
            {
                const float* xsrc = &X[((size_t)(g * 16 + urow) * S_ + (t + 1)) * D_ + ucol * 8];
                xr0 = *(const float4*)xsrc;
                xr1 = *(const float4*)(xsrc + 4);
            }

            if (tid == 0) {
                __hip_atomic_fetch_add(&cnt[g], 1u, __ATOMIC_RELEASE, __HIP_MEMORY_SCOPE_AGENT);
                unsigned int target = 8u * (unsigned int)(t + 1);
                while (__hip_atomic_load(&cnt[g], __ATOMIC_RELAXED, __HIP_MEMORY_SCOPE_AGENT) < target) {
                    __builtin_amdgcn_s_sleep(2);
                }
            }
            __syncthreads();                                   // all threads wait for poller
            __builtin_amdgcn_fence(__ATOMIC_ACQUIRE, "agent"); // invalidate L1/L2 (no traffic)
        }
    }
}

__global__ void pred_fin(const float* __restrict__ pred,
                         const float* __restrict__ bfc,
                         float* __restrict__ out)
{
    int i = blockIdx.x * blockDim.x + threadIdx.x;
    if (i < B_ * S_) out[i] = pred[i] + bfc[0];
}

extern "C" void kernel_launch(void* const* d_in, const int* in_sizes, int n_in,
                              void* d_out, int out_size, void* d_ws, size_t ws_size,
                              hipStream_t stream) {
    const float* X   = (const float*)d_in[0];
    const float* Wf  = (const float*)d_in[1];
    const float* Wi  = (const float*)d_in[2];
    const float* Wo  = (const float*)d_in[3];
    const float* Wc  = (const float*)d_in[4];
    const float* bfp = (const float*)d_in[5];
    const float* bip = (const float*)d_in[6];
    const float* bop = (const float*)d_in[7];
    const float* bcp = (const float*)d_in[8];
    const float* Uf  = (const float*)d_in[9];
    const float* Ui  = (const float*)d_in[10];
    const float* Uo  = (const float*)d_in[11];
    const float* Uc  = (const float*)d_in[12];
    const float* Wfc = (const float*)d_in[13];
    const float* bfc = (const float*)d_in[14];

    // ws layout: pred fp32 [64][512] @0 (128KB) | hbuf bf16 [3][64][512] @131072 (192KB) | counters @327680
    float*        pred = (float*)d_ws;
    ushort_t*     hbuf = (ushort_t*)((char*)d_ws + 131072);
    unsigned int* cnt  = (unsigned int*)((char*)d_ws + 131072 + 196608);

    hipMemsetAsync(d_ws, 0, 131072 + 196608 + 256, stream);   // zero pred, h(0), counters

    float* out = (float*)d_out;
    lstm_rec<<<32, 512, 0, stream>>>(X, Wf, Wi, Wo, Wc, bfp, bip, bop, bcp,
                                     Uf, Ui, Uo, Uc, Wfc,
                                     pred, hbuf, cnt,
                                     out + 32768, out + 65536);
    pred_fin<<<128, 256, 0, stream>>>(pred, bfc, out);
}

// Round 4
// 2940.718 us; speedup vs baseline: 2.4135x; 1.0199x over previous
//
#include <hip/hip_runtime.h>
#include <hip/hip_bf16.h>

#define B_ 64
#define S_ 512
#define D_ 256
#define H_ 512

typedef __attribute__((ext_vector_type(8))) short bf16x8;
typedef __attribute__((ext_vector_type(4))) float f32x4;
typedef unsigned short ushort_t;

__device__ __forceinline__ ushort_t f2bf(float f) {
    __hip_bfloat16 h = __float2bfloat16(f);   // RNE rounding
    return *reinterpret_cast<ushort_t*>(&h);
}
__device__ __forceinline__ float sigmoid_f(float x) { return 1.f / (1.f + __expf(-x)); }
__device__ __forceinline__ float tanh_f(float x) { return 1.f - 2.f / (__expf(2.f * x) + 1.f); }

// grid: 32 blocks x 512 threads.
// block: group g = blockIdx&3 (batch rows g*16..g*16+15), slice s = blockIdx>>2 (0..7, h-cols s*64..s*64+63)
// wave w (0..7): gate = w>>1 (f,i,o,chat), half = w&1 -> two 16-col n-tiles (ncol0, ncol0+16).
// U/Wx B-fragments in VGPRs for the whole kernel (fp32->bf16 RNE once).
// h exchange is CACHE-BYPASSING: stores/loads are relaxed agent-scope atomics (sc0 sc1,
// write-through to L3 / read from L3). No acquire fence, no L2 writeback/invalidate per step.
__global__ __launch_bounds__(512, 2) void lstm_rec(
    const float* __restrict__ X,
    const float* __restrict__ Wf, const float* __restrict__ Wi,
    const float* __restrict__ Wo, const float* __restrict__ Wc,
    const float* __restrict__ bfp, const float* __restrict__ bip,
    const float* __restrict__ bop, const float* __restrict__ bcp,
    const float* __restrict__ Uf, const float* __restrict__ Ui,
    const float* __restrict__ Uo, const float* __restrict__ Uc,
    const float* __restrict__ Wfc,
    float* __restrict__ pred, unsigned int* __restrict__ hbufU,
    unsigned int* __restrict__ cnt,
    float* __restrict__ outH, float* __restrict__ outC)
{
    __shared__ ushort_t hS[16 * 520];   // 520-short stride: 16B-aligned rows
    __shared__ ushort_t xS[16 * 264];
    __shared__ float gact[4][16][68];
    __shared__ float cS[16][64];        // thread owns a float2-aligned pair

    const int tid  = threadIdx.x;
    const int w    = tid >> 6;
    const int lane = tid & 63;
    const int q    = lane >> 4;      // quad for MFMA frag layout
    const int m    = lane & 15;      // A-row / B-col lane index
    const int gate = w >> 1;
    const int half = w & 1;
    const int g    = blockIdx.x & 3;
    const int s    = blockIdx.x >> 2;

    const int ncol0 = s * 64 + half * 32 + m;
    const int ncol1 = ncol0 + 16;

    const float* Ug = (gate == 0) ? Uf : (gate == 1) ? Ui : (gate == 2) ? Uo : Uc;
    const float* Wg = (gate == 0) ? Wf : (gate == 1) ? Wi : (gate == 2) ? Wo : Wc;
    const float* bg = (gate == 0) ? bfp : (gate == 1) ? bip : (gate == 2) ? bop : bcp;

    const float bias0 = bg[ncol0];
    const float bias1 = bg[ncol1];

    // ---- one-time: load B-fragments into registers (fp32 -> bf16 RNE) ----
    bf16x8 UF[2][16];
    bf16x8 WF[2][8];
    #pragma unroll
    for (int tt = 0; tt < 2; ++tt) {
        const int nc = tt ? ncol1 : ncol0;
        #pragma unroll
        for (int ks = 0; ks < 16; ++ks) {
            bf16x8 v;
            #pragma unroll
            for (int j = 0; j < 8; ++j) {
                int k = ks * 32 + q * 8 + j;
                v[j] = (short)f2bf(Ug[k * H_ + nc]);
            }
            UF[tt][ks] = v;
        }
        #pragma unroll
        for (int ks = 0; ks < 8; ++ks) {
            bf16x8 v;
            #pragma unroll
            for (int j = 0; j < 8; ++j) {
                int k = ks * 32 + q * 8 + j;
                v[j] = (short)f2bf(Wg[k * H_ + nc]);
            }
            WF[tt][ks] = v;
        }
    }

    const int urow  = tid >> 5;   // update-phase row (batch within group), 0..15
    const int upair = tid & 31;   // update-phase col-pair: owns cols 2*upair, 2*upair+1
    const float2 wfc2 = *(const float2*)&Wfc[s * 64 + 2 * upair];

    *(float2*)&cS[urow][2 * upair] = make_float2(0.f, 0.f);   // c0 = 0

    // preload x(0) into registers (row=urow, 8 floats at col upair*8)
    float4 xr0, xr1;
    {
        const float* xsrc = &X[((size_t)(g * 16 + urow) * S_ + 0) * D_ + upair * 8];
        xr0 = *(const float4*)xsrc;
        xr1 = *(const float4*)(xsrc + 4);
    }

    for (int t = 0; t < S_; ++t) {
        // ---- stage x(t) (from prefetch regs) into LDS ----
        {
            bf16x8 v;
            v[0] = (short)f2bf(xr0.x); v[1] = (short)f2bf(xr0.y);
            v[2] = (short)f2bf(xr0.z); v[3] = (short)f2bf(xr0.w);
            v[4] = (short)f2bf(xr1.x); v[5] = (short)f2bf(xr1.y);
            v[6] = (short)f2bf(xr1.z); v[7] = (short)f2bf(xr1.w);
            *(bf16x8*)&xS[urow * 264 + upair * 8] = v;
        }
        // ---- stage h(t) [16 x 512] via cache-bypassing dword loads (read from L3) ----
        #pragma unroll
        for (int it = 0; it < 8; ++it) {
            int idx  = it * 512 + tid;          // 0..4095 dwords
            int row  = idx >> 8;                // 0..15
            int dcol = idx & 255;               // dword col (2 bf16 each)
            unsigned int u = __hip_atomic_load(
                &hbufU[(size_t)((t % 3) * B_ + g * 16 + row) * 256 + dcol],
                __ATOMIC_RELAXED, __HIP_MEMORY_SCOPE_AGENT);
            *(unsigned int*)&hS[row * 520 + dcol * 2] = u;
        }
        __syncthreads();

        // ---- g = bias + x.W + h.U for this wave's 2 x 16 columns (4 indep acc chains) ----
        f32x4 accA0 = {bias0, bias0, bias0, bias0};
        f32x4 accA1 = {bias1, bias1, bias1, bias1};
        f32x4 accB0 = {0.f, 0.f, 0.f, 0.f};
        f32x4 accB1 = {0.f, 0.f, 0.f, 0.f};
        #pragma unroll
        for (int ks = 0; ks < 8; ++ks) {
            bf16x8 a = *(const bf16x8*)&xS[m * 264 + ks * 32 + q * 8];
            accA0 = __builtin_amdgcn_mfma_f32_16x16x32_bf16(a, WF[0][ks], accA0, 0, 0, 0);
            accA1 = __builtin_amdgcn_mfma_f32_16x16x32_bf16(a, WF[1][ks], accA1, 0, 0, 0);
        }
        #pragma unroll
        for (int ks = 0; ks < 16; ++ks) {
            bf16x8 a = *(const bf16x8*)&hS[m * 520 + ks * 32 + q * 8];
            accB0 = __builtin_amdgcn_mfma_f32_16x16x32_bf16(a, UF[0][ks], accB0, 0, 0, 0);
            accB1 = __builtin_amdgcn_mfma_f32_16x16x32_bf16(a, UF[1][ks], accB1, 0, 0, 0);
        }

        // activation; C-layout: col = lane&15, row = q*4 + j
        #pragma unroll
        for (int j = 0; j < 4; ++j) {
            float v0 = accA0[j] + accB0[j];
            float v1 = accA1[j] + accB1[j];
            v0 = (gate < 3) ? sigmoid_f(v0) : tanh_f(v0);
            v1 = (gate < 3) ? sigmoid_f(v1) : tanh_f(v1);
            gact[gate][q * 4 + j][half * 32 + m]      = v0;
            gact[gate][q * 4 + j][half * 32 + 16 + m] = v1;
        }
        __syncthreads();

        // ---- state update: thread owns (urow, 2*upair) and (urow, 2*upair+1) ----
        float2 f2v  = *(const float2*)&gact[0][urow][2 * upair];
        float2 i2v  = *(const float2*)&gact[1][urow][2 * upair];
        float2 o2v  = *(const float2*)&gact[2][urow][2 * upair];
        float2 ch2  = *(const float2*)&gact[3][urow][2 * upair];
        float2 c2   = *(const float2*)&cS[urow][2 * upair];
        float cn0 = f2v.x * c2.x + i2v.x * ch2.x;
        float cn1 = f2v.y * c2.y + i2v.y * ch2.y;
        *(float2*)&cS[urow][2 * upair] = make_float2(cn0, cn1);
        float hv0 = o2v.x * tanh_f(cn0);
        float hv1 = o2v.y * tanh_f(cn1);

        // write-through packed dword to L3 (never dirty in L2)
        unsigned int packed = (unsigned int)f2bf(hv0) | ((unsigned int)f2bf(hv1) << 16);
        __hip_atomic_store(
            &hbufU[(size_t)(((t + 1) % 3) * B_ + g * 16 + urow) * 256 + s * 32 + upair],
            packed, __ATOMIC_RELAXED, __HIP_MEMORY_SCOPE_AGENT);

        // fused prediction head: reduce 32 lanes (one row per half-wave) + 1 atomic
        float pv = hv0 * wfc2.x + hv1 * wfc2.y;
        pv += __shfl_xor(pv, 16);
        pv += __shfl_xor(pv, 8);
        pv += __shfl_xor(pv, 4);
        pv += __shfl_xor(pv, 2);
        pv += __shfl_xor(pv, 1);
        if (upair == 0) atomicAdd(&pred[(g * 16 + urow) * S_ + t], pv);

        if (t == S_ - 1) {
            *(float2*)&outH[(g * 16 + urow) * H_ + s * 64 + 2 * upair] = make_float2(hv0, hv1);
            *(float2*)&outC[(g * 16 + urow) * H_ + s * 64 + 2 * upair] = make_float2(cn0, cn1);
        } else {
            // ---- inter-block barrier for this batch group (single poller) ----
            __syncthreads();   // drains vmcnt: all h stores complete (at L3) before release

            // prefetch x(t+1) into registers while the poller waits
            {
                const float* xsrc = &X[((size_t)(g * 16 + urow) * S_ + (t + 1)) * D_ + upair * 8];
                xr0 = *(const float4*)xsrc;
                xr1 = *(const float4*)(xsrc + 4);
            }

            if (tid == 0) {
                __hip_atomic_fetch_add(&cnt[g * 64], 1u, __ATOMIC_RELEASE, __HIP_MEMORY_SCOPE_AGENT);
                unsigned int target = 8u * (unsigned int)(t + 1);
                while (__hip_atomic_load(&cnt[g * 64], __ATOMIC_RELAXED, __HIP_MEMORY_SCOPE_AGENT) < target) {
                    __builtin_amdgcn_s_sleep(1);
                }
            }
            __syncthreads();   // all threads wait for poller; no fence needed:
                               // h loads bypass L1/L2 and read L3, where release put the data
        }
    }
}

__global__ void pred_fin(const float* __restrict__ pred,
                         const float* __restrict__ bfc,
                         float* __restrict__ out)
{
    int i = blockIdx.x * blockDim.x + threadIdx.x;
    if (i < B_ * S_) out[i] = pred[i] + bfc[0];
}

extern "C" void kernel_launch(void* const* d_in, const int* in_sizes, int n_in,
                              void* d_out, int out_size, void* d_ws, size_t ws_size,
                              hipStream_t stream) {
    const float* X   = (const float*)d_in[0];
    const float* Wf  = (const float*)d_in[1];
    const float* Wi  = (const float*)d_in[2];
    const float* Wo  = (const float*)d_in[3];
    const float* Wc  = (const float*)d_in[4];
    const float* bfp = (const float*)d_in[5];
    const float* bip = (const float*)d_in[6];
    const float* bop = (const float*)d_in[7];
    const float* bcp = (const float*)d_in[8];
    const float* Uf  = (const float*)d_in[9];
    const float* Ui  = (const float*)d_in[10];
    const float* Uo  = (const float*)d_in[11];
    const float* Uc  = (const float*)d_in[12];
    const float* Wfc = (const float*)d_in[13];
    const float* bfc = (const float*)d_in[14];

    // ws layout: pred fp32 [64][512] @0 (128KB) | hbuf bf16 [3][64][512] @131072 (192KB)
    //            | counters @327680 (4 groups x 256B)
    float*        pred  = (float*)d_ws;
    unsigned int* hbufU = (unsigned int*)((char*)d_ws + 131072);
    unsigned int* cnt   = (unsigned int*)((char*)d_ws + 131072 + 196608);

    hipMemsetAsync(d_ws, 0, 131072 + 196608 + 1024, stream);   // zero pred, h(0), counters

    float* out = (float*)d_out;
    lstm_rec<<<32, 512, 0, stream>>>(X, Wf, Wi, Wo, Wc, bfp, bip, bop, bcp,
                                     Uf, Ui, Uo, Uc, Wfc,
                                     pred, hbufU, cnt,
                                     out + 32768, out + 65536);
    pred_fin<<<128, 256, 0, stream>>>(pred, bfc, out);
}

// Round 5
// 2410.988 us; speedup vs baseline: 2.9437x; 1.2197x over previous
//
#include <hip/hip_runtime.h>
#include <hip/hip_bf16.h>

#define B_ 64
#define S_ 512
#define D_ 256
#define H_ 512

typedef __attribute__((ext_vector_type(8))) short bf16x8;
typedef __attribute__((ext_vector_type(4))) float f32x4;
typedef __attribute__((ext_vector_type(4))) unsigned int uint4v;
typedef unsigned short ushort_t;

__device__ __forceinline__ ushort_t f2bf(float f) {
    __hip_bfloat16 h = __float2bfloat16(f);   // RNE rounding
    return *reinterpret_cast<ushort_t*>(&h);
}
__device__ __forceinline__ float sigmoid_f(float x) { return 1.f / (1.f + __expf(-x)); }
__device__ __forceinline__ float tanh_f(float x) { return 1.f - 2.f / (__expf(2.f * x) + 1.f); }

// grid: 32 blocks x 512 threads.
// block: group g = blockIdx&3 (batch rows g*16..+15), slice s = blockIdx>>2 (h-cols s*64..+63)
// wave w: gate = w>>1, half = w&1 -> two 16-col n-tiles (ncol0, ncol0+16).
// U/Wx B-fragments in VGPRs (fp32->bf16 RNE once). h exchange write-through to L3
// (sc0 sc1), loads read L3 directly. Phase schedule packs all long-latency vmem
// (h-load, x-prefetch) into ONE phase and keeps the pred RMW under MFMA compute,
// because every __syncthreads drains vmcnt(0).
__global__ __launch_bounds__(512, 2) void lstm_rec(
    const float* __restrict__ X,
    const float* __restrict__ Wf, const float* __restrict__ Wi,
    const float* __restrict__ Wo, const float* __restrict__ Wc,
    const float* __restrict__ bfp, const float* __restrict__ bip,
    const float* __restrict__ bop, const float* __restrict__ bcp,
    const float* __restrict__ Uf, const float* __restrict__ Ui,
    const float* __restrict__ Uo, const float* __restrict__ Uc,
    const float* __restrict__ Wfc,
    float* __restrict__ pred, unsigned int* __restrict__ hbufU,
    unsigned int* __restrict__ cnt,
    float* __restrict__ outH, float* __restrict__ outC)
{
    __shared__ ushort_t hS[16 * 520];   // 520-short stride: 16B-aligned rows
    __shared__ ushort_t xS[16 * 264];
    __shared__ float gact[4][16][68];

    const int tid  = threadIdx.x;
    const int w    = tid >> 6;
    const int lane = tid & 63;
    const int q    = lane >> 4;      // quad for MFMA frag layout
    const int m    = lane & 15;      // A-row / B-col lane index
    const int gate = w >> 1;
    const int half = w & 1;
    const int g    = blockIdx.x & 3;
    const int s    = blockIdx.x >> 2;

    const int ncol0 = s * 64 + half * 32 + m;
    const int ncol1 = ncol0 + 16;

    const float* Ug = (gate == 0) ? Uf : (gate == 1) ? Ui : (gate == 2) ? Uo : Uc;
    const float* Wg = (gate == 0) ? Wf : (gate == 1) ? Wi : (gate == 2) ? Wo : Wc;
    const float* bg = (gate == 0) ? bfp : (gate == 1) ? bip : (gate == 2) ? bop : bcp;

    const float bias0 = bg[ncol0];
    const float bias1 = bg[ncol1];

    // ---- one-time: load B-fragments into registers (fp32 -> bf16 RNE) ----
    bf16x8 UF[2][16];
    bf16x8 WF[2][8];
    #pragma unroll
    for (int tt = 0; tt < 2; ++tt) {
        const int nc = tt ? ncol1 : ncol0;
        #pragma unroll
        for (int ks = 0; ks < 16; ++ks) {
            bf16x8 v;
            #pragma unroll
            for (int j = 0; j < 8; ++j) {
                int k = ks * 32 + q * 8 + j;
                v[j] = (short)f2bf(Ug[k * H_ + nc]);
            }
            UF[tt][ks] = v;
        }
        #pragma unroll
        for (int ks = 0; ks < 8; ++ks) {
            bf16x8 v;
            #pragma unroll
            for (int j = 0; j < 8; ++j) {
                int k = ks * 32 + q * 8 + j;
                v[j] = (short)f2bf(Wg[k * H_ + nc]);
            }
            WF[tt][ks] = v;
        }
    }

    const int urow  = tid >> 5;   // update-phase row (batch within group), 0..15
    const int upair = tid & 31;   // update-phase col-pair: owns cols 2*upair, 2*upair+1
    const float2 wfc2 = *(const float2*)&Wfc[s * 64 + 2 * upair];

    float cr0 = 0.f, cr1 = 0.f;   // c-state lives in registers (thread-exclusive)
    float pv_prev = 0.f;

    // ---- preamble: stage x(0) into LDS (ordered by barrier B of iteration 0) ----
    {
        const float* xsrc = &X[((size_t)(g * 16 + urow) * S_ + 0) * D_ + upair * 8];
        float4 a = *(const float4*)xsrc;
        float4 b = *(const float4*)(xsrc + 4);
        bf16x8 v;
        v[0] = (short)f2bf(a.x); v[1] = (short)f2bf(a.y);
        v[2] = (short)f2bf(a.z); v[3] = (short)f2bf(a.w);
        v[4] = (short)f2bf(b.x); v[5] = (short)f2bf(b.y);
        v[6] = (short)f2bf(b.z); v[7] = (short)f2bf(b.w);
        *(bf16x8*)&xS[urow * 264 + upair * 8] = v;
    }

    float4 xr0, xr1;   // x(t+1) prefetch registers

    for (int t = 0; t < S_; ++t) {
        // ---- A: confirm h(t) posted by all 8 blocks of this group ----
        if (t > 0 && tid == 0) {
            unsigned int target = 8u * (unsigned int)t;
            while (__hip_atomic_load(&cnt[g * 64], __ATOMIC_RELAXED, __HIP_MEMORY_SCOPE_AGENT) < target) {
                __builtin_amdgcn_s_sleep(1);
            }
        }
        __syncthreads();   // B (no vmem pending here — cheap)

        // ---- C: ALL long-latency vmem in one phase (x-HBM || h-L3 overlap) ----
        if (t + 1 < S_) {
            const float* xsrc = &X[((size_t)(g * 16 + urow) * S_ + (t + 1)) * D_ + upair * 8];
            xr0 = *(const float4*)xsrc;
            xr1 = *(const float4*)(xsrc + 4);
        }
        {
            const int row  = tid >> 5;
            const int dcol = (tid & 31) * 8;
            const unsigned int* p0 = &hbufU[(size_t)((t % 3) * B_ + g * 16 + row) * 256 + dcol];
            const unsigned int* p1 = p0 + 4;
            uint4v ra, rb;
            asm volatile(
                "global_load_dwordx4 %0, %2, off sc0 sc1\n\t"
                "global_load_dwordx4 %1, %3, off sc0 sc1\n\t"
                "s_waitcnt vmcnt(0)"
                : "=v"(ra), "=v"(rb) : "v"(p0), "v"(p1) : "memory");
            *(uint4v*)&hS[row * 520 + dcol * 2]     = ra;
            *(uint4v*)&hS[row * 520 + dcol * 2 + 8] = rb;
        }
        __syncthreads();   // D

        // ---- E: pred RMW (hides under MFMA) + gate GEMMs + activations ----
        if (t > 0 && upair == 0) {
            atomicAdd(&pred[(g * 16 + urow) * S_ + (t - 1)], pv_prev);
        }
        f32x4 accA0 = {bias0, bias0, bias0, bias0};
        f32x4 accA1 = {bias1, bias1, bias1, bias1};
        f32x4 accB0 = {0.f, 0.f, 0.f, 0.f};
        f32x4 accB1 = {0.f, 0.f, 0.f, 0.f};
        #pragma unroll
        for (int ks = 0; ks < 8; ++ks) {
            bf16x8 a = *(const bf16x8*)&xS[m * 264 + ks * 32 + q * 8];
            accA0 = __builtin_amdgcn_mfma_f32_16x16x32_bf16(a, WF[0][ks], accA0, 0, 0, 0);
            accA1 = __builtin_amdgcn_mfma_f32_16x16x32_bf16(a, WF[1][ks], accA1, 0, 0, 0);
        }
        #pragma unroll
        for (int ks = 0; ks < 16; ++ks) {
            bf16x8 a = *(const bf16x8*)&hS[m * 520 + ks * 32 + q * 8];
            accB0 = __builtin_amdgcn_mfma_f32_16x16x32_bf16(a, UF[0][ks], accB0, 0, 0, 0);
            accB1 = __builtin_amdgcn_mfma_f32_16x16x32_bf16(a, UF[1][ks], accB1, 0, 0, 0);
        }
        #pragma unroll
        for (int j = 0; j < 4; ++j) {
            float v0 = accA0[j] + accB0[j];
            float v1 = accA1[j] + accB1[j];
            v0 = (gate < 3) ? sigmoid_f(v0) : tanh_f(v0);
            v1 = (gate < 3) ? sigmoid_f(v1) : tanh_f(v1);
            gact[gate][q * 4 + j][half * 32 + m]      = v0;
            gact[gate][q * 4 + j][half * 32 + 16 + m] = v1;
        }
        __syncthreads();   // F

        // ---- G: state update (c in registers), h(t+1) write-through, xS(t+1) ----
        float2 f2v = *(const float2*)&gact[0][urow][2 * upair];
        float2 i2v = *(const float2*)&gact[1][urow][2 * upair];
        float2 o2v = *(const float2*)&gact[2][urow][2 * upair];
        float2 ch2 = *(const float2*)&gact[3][urow][2 * upair];
        cr0 = f2v.x * cr0 + i2v.x * ch2.x;
        cr1 = f2v.y * cr1 + i2v.y * ch2.y;
        float hv0 = o2v.x * tanh_f(cr0);
        float hv1 = o2v.y * tanh_f(cr1);

        float pv = hv0 * wfc2.x + hv1 * wfc2.y;
        pv += __shfl_xor(pv, 16);
        pv += __shfl_xor(pv, 8);
        pv += __shfl_xor(pv, 4);
        pv += __shfl_xor(pv, 2);
        pv += __shfl_xor(pv, 1);
        pv_prev = pv;   // RMW deferred to next iteration's phase E

        if (t < S_ - 1) {
            unsigned int packed = (unsigned int)f2bf(hv0) | ((unsigned int)f2bf(hv1) << 16);
            __hip_atomic_store(
                &hbufU[(size_t)(((t + 1) % 3) * B_ + g * 16 + urow) * 256 + s * 32 + upair],
                packed, __ATOMIC_RELAXED, __HIP_MEMORY_SCOPE_AGENT);

            // stage x(t+1) from prefetch regs (latency already absorbed in C)
            bf16x8 v;
            v[0] = (short)f2bf(xr0.x); v[1] = (short)f2bf(xr0.y);
            v[2] = (short)f2bf(xr0.z); v[3] = (short)f2bf(xr0.w);
            v[4] = (short)f2bf(xr1.x); v[5] = (short)f2bf(xr1.y);
            v[6] = (short)f2bf(xr1.z); v[7] = (short)f2bf(xr1.w);
            *(bf16x8*)&xS[urow * 264 + upair * 8] = v;

            // ---- H: drain h stores, then release ----
            __syncthreads();
            if (tid == 0) {
                __hip_atomic_fetch_add(&cnt[g * 64], 1u, __ATOMIC_RELEASE, __HIP_MEMORY_SCOPE_AGENT);
            }
        } else {
            *(float2*)&outH[(g * 16 + urow) * H_ + s * 64 + 2 * upair] = make_float2(hv0, hv1);
            *(float2*)&outC[(g * 16 + urow) * H_ + s * 64 + 2 * upair] = make_float2(cr0, cr1);
            if (upair == 0) atomicAdd(&pred[(g * 16 + urow) * S_ + t], pv_prev);
        }
    }
}

__global__ void pred_fin(const float* __restrict__ pred,
                         const float* __restrict__ bfc,
                         float* __restrict__ out)
{
    int i = blockIdx.x * blockDim.x + threadIdx.x;
    if (i < B_ * S_) out[i] = pred[i] + bfc[0];
}

extern "C" void kernel_launch(void* const* d_in, const int* in_sizes, int n_in,
                              void* d_out, int out_size, void* d_ws, size_t ws_size,
                              hipStream_t stream) {
    const float* X   = (const float*)d_in[0];
    const float* Wf  = (const float*)d_in[1];
    const float* Wi  = (const float*)d_in[2];
    const float* Wo  = (const float*)d_in[3];
    const float* Wc  = (const float*)d_in[4];
    const float* bfp = (const float*)d_in[5];
    const float* bip = (const float*)d_in[6];
    const float* bop = (const float*)d_in[7];
    const float* bcp = (const float*)d_in[8];
    const float* Uf  = (const float*)d_in[9];
    const float* Ui  = (const float*)d_in[10];
    const float* Uo  = (const float*)d_in[11];
    const float* Uc  = (const float*)d_in[12];
    const float* Wfc = (const float*)d_in[13];
    const float* bfc = (const float*)d_in[14];

    // ws layout: pred fp32 [64][512] @0 (128KB) | hbuf bf16 [3][64][512] @131072 (192KB)
    //            | counters @327680 (4 groups x 256B)
    float*        pred  = (float*)d_ws;
    unsigned int* hbufU = (unsigned int*)((char*)d_ws + 131072);
    unsigned int* cnt   = (unsigned int*)((char*)d_ws + 131072 + 196608);

    hipMemsetAsync(d_ws, 0, 131072 + 196608 + 1024, stream);   // zero pred, h(0), counters

    float* out = (float*)d_out;
    lstm_rec<<<32, 512, 0, stream>>>(X, Wf, Wi, Wo, Wc, bfp, bip, bop, bcp,
                                     Uf, Ui, Uo, Uc, Wfc,
                                     pred, hbufU, cnt,
                                     out + 32768, out + 65536);
    pred_fin<<<128, 256, 0, stream>>>(pred, bfc, out);
}